// Round 19
// baseline (296.814 us; speedup 1.0000x reference)
//
#include <hip/hip_runtime.h>

#define NSTAT 32
#define MAXSEL 76

typedef __attribute__((ext_vector_type(8))) short bf16x8_t;
typedef __attribute__((ext_vector_type(4))) float f32x4_t;

#define GLOAD_LDS16(g, l) \
    __builtin_amdgcn_global_load_lds((const __attribute__((address_space(1))) void*)(g), \
                                     (__attribute__((address_space(3))) void*)(l), 16, 0, 0)

// round-to-nearest-even bf16
__device__ __forceinline__ ushort rtn_bf16(float a) {
    unsigned u = __float_as_uint(a);
    return (ushort)((u + 0x7FFFu + ((u >> 16) & 1u)) >> 16);
}
// 2-limb RTN decomposition: a ~= hi + lo, |residual| <= 2^-18 |a|
__device__ __forceinline__ void limb2(float a, ushort& h, ushort& l) {
    ushort hh = rtn_bf16(a);
    float fh = __uint_as_float(((unsigned)hh) << 16);
    float r1 = a - fh;
    l = rtn_bf16(r1);
    h = hh;
}

// ---------------- weight 2-limb decomposition (pre-swizzled tile layout) ----------------
__global__ __launch_bounds__(256)
void decomp_w_kernel(const float* __restrict__ Wq, const float* __restrict__ Wk,
                     const float* __restrict__ Wv, const float* __restrict__ Wo,
                     ushort* __restrict__ WLq, ushort* __restrict__ WoLb)
{
    const int m = blockIdx.y;
    const float* src = (m == 0) ? Wq : (m == 1) ? Wk : (m == 2) ? Wv : Wo;
    const int idx = blockIdx.x * 256 + threadIdx.x;
    const int e8 = idx * 8;
    const int row = e8 >> 10, k0 = e8 & 1023;
    const int kt = k0 >> 5, q = (k0 >> 3) & 3;
    const size_t doff = ((size_t)row << 10) + (size_t)(kt * 32) + (size_t)((q ^ (row & 3)) * 8);

    float4 v0 = *(const float4*)(src + e8);
    float4 v1 = *(const float4*)(src + e8 + 4);
    float f[8] = {v0.x, v0.y, v0.z, v0.w, v1.x, v1.y, v1.z, v1.w};

    const size_t Mi = (size_t)1 << 20;
    ushort h[8], l[8];
    #pragma unroll
    for (int e = 0; e < 8; ++e) limb2(f[e], h[e], l[e]);
    ushort* H = (m == 3) ? WoLb : WLq + (size_t)(m * 2) * Mi;
    ushort* L = H + Mi;
    *(ushort4*)(H + doff)     = make_ushort4(h[0],h[1],h[2],h[3]);
    *(ushort4*)(H + doff + 4) = make_ushort4(h[4],h[5],h[6],h[7]);
    *(ushort4*)(L + doff)     = make_ushort4(l[0],l[1],l[2],l[3]);
    *(ushort4*)(L + doff + 4) = make_ushort4(l[4],l[5],l[6],l[7]);
}

// ---------------- 2-limb MFMA GEMM (R8-validated; A fp32 on-the-fly) ----------------
__global__ __launch_bounds__(256, 3)
void limb_gemm_kernel(const float* __restrict__ A,
                      const ushort* __restrict__ WLq, const ushort* __restrict__ WoLb,
                      const float* __restrict__ bq, const float* __restrict__ bk,
                      const float* __restrict__ bv, const float* __restrict__ bo,
                      const float* __restrict__ statk,
                      float* __restrict__ Qw, float* __restrict__ Vw,
                      ushort* __restrict__ KHo, ushort* __restrict__ KLo,
                      float* __restrict__ Cout, int is_out)
{
    __shared__ __align__(16) ushort Al[2][128][32];
    __shared__ __align__(16) ushort Bl[2][2][128][32];

    const int t = threadIdx.x;
    const int bx = blockIdx.x, by = blockIdx.y;
    const int mode = is_out ? 3 : (int)blockIdx.z;
    const int wc0 = bx * 128;
    const int arow0 = by * 128;

    const size_t Mi = (size_t)1 << 20;
    const ushort* BpH;
    const float* bias;
    if (mode == 0)      { BpH = WLq;          bias = bq; }
    else if (mode == 1) { BpH = WLq + 2*Mi;   bias = bk; }
    else if (mode == 2) { BpH = WLq + 4*Mi;   bias = bv; }
    else                { BpH = WoLb;         bias = bo; }
    const ushort* BpL = BpH + Mi;

    const int ll = t & 63, w = t >> 6;

    f32x4_t acc[4][4];
    #pragma unroll
    for (int i = 0; i < 4; ++i)
        #pragma unroll
        for (int j = 0; j < 4; ++j) acc[i][j] = (f32x4_t){0.f, 0.f, 0.f, 0.f};

    auto stageB = [&](int kt, int bb) {
        #pragma unroll
        for (int limb = 0; limb < 2; ++limb) {
            const ushort* src = limb ? BpL : BpH;
            #pragma unroll
            for (int call = 0; call < 2; ++call) {
                int chunk = (w * 2 + call) * 64 + ll;
                int eoff = chunk * 8;
                int row = eoff >> 5, qp = (eoff >> 3) & 3;
                const ushort* g = src + ((size_t)(wc0 + row) << 10) + kt * 32 + qp * 8;
                char* l = ((char*)&Bl[bb][limb][0][0]) + (w * 2 + call) * 1024;
                GLOAD_LDS16(g, l);
            }
        }
    };
    const int srow = t >> 1, skh = (t & 1) * 16;
    auto loadA = [&](int kt, float4* a4) {
        const float* p = A + (((size_t)(arow0 + srow)) << 10) + kt * 32 + skh;
        a4[0] = *(const float4*)(p + 0);
        a4[1] = *(const float4*)(p + 4);
        a4[2] = *(const float4*)(p + 8);
        a4[3] = *(const float4*)(p + 12);
    };
    auto writeA = [&](const float4* a4) {
        float f[16];
        #pragma unroll
        for (int i = 0; i < 4; ++i) {
            f[i*4+0] = a4[i].x; f[i*4+1] = a4[i].y; f[i*4+2] = a4[i].z; f[i*4+3] = a4[i].w;
        }
        ushort h[16], lo[16];
        #pragma unroll
        for (int e = 0; e < 16; ++e) limb2(f[e], h[e], lo[e]);
        const int sw = srow & 3;
        #pragma unroll
        for (int qq = 0; qq < 2; ++qq) {
            int q = (skh >> 3) + qq;
            int qo = (q ^ sw) * 8;
            bf16x8_t vH, vL;
            #pragma unroll
            for (int e = 0; e < 8; ++e) {
                vH[e] = (short)h[qq*8+e]; vL[e] = (short)lo[qq*8+e];
            }
            *(bf16x8_t*)&Al[0][srow][qo] = vH;
            *(bf16x8_t*)&Al[1][srow][qo] = vL;
        }
    };

    const int wr = (w >> 1) * 64, wcv = (w & 1) * 64;
    const int fr = ll & 15, kg = ll >> 4;

    auto compute = [&](int bb) {
        bf16x8_t af[4][2];
        #pragma unroll
        for (int i = 0; i < 4; ++i) {
            int row = wr + i * 16 + fr;
            int qo = (kg ^ (row & 3)) * 8;
            af[i][0] = *(const bf16x8_t*)&Al[0][row][qo];
            af[i][1] = *(const bf16x8_t*)&Al[1][row][qo];
        }
        #pragma unroll
        for (int j = 0; j < 4; ++j) {
            int row = wcv + j * 16 + fr;
            int qo = (kg ^ (row & 3)) * 8;
            bf16x8_t b0 = *(const bf16x8_t*)&Bl[bb][0][row][qo];
            bf16x8_t b1 = *(const bf16x8_t*)&Bl[bb][1][row][qo];
            #pragma unroll
            for (int i = 0; i < 4; ++i) {
                acc[i][j] = __builtin_amdgcn_mfma_f32_16x16x32_bf16(af[i][0], b0, acc[i][j], 0, 0, 0);
                acc[i][j] = __builtin_amdgcn_mfma_f32_16x16x32_bf16(af[i][0], b1, acc[i][j], 0, 0, 0);
                acc[i][j] = __builtin_amdgcn_mfma_f32_16x16x32_bf16(af[i][1], b0, acc[i][j], 0, 0, 0);
            }
        }
    };

    float4 a4[4];
    loadA(0, a4);
    writeA(a4);
    stageB(0, 0);
    __syncthreads();

    float4 a4n[4];
    for (int kt = 0; kt < 32; ++kt) {
        int bb = kt & 1;
        if (kt < 31) {
            stageB(kt + 1, bb ^ 1);
            loadA(kt + 1, a4n);
        }
        compute(bb);
        __syncthreads();
        if (kt < 31) writeA(a4n);
        __syncthreads();
    }

    #pragma unroll
    for (int i = 0; i < 4; ++i) {
        #pragma unroll
        for (int j = 0; j < 4; ++j) {
            int c = wc0 + wcv + j * 16 + (ll & 15);
            float bv_ = bias[c];
            #pragma unroll
            for (int q = 0; q < 4; ++q) {
                int gr = arow0 + wr + i * 16 + (kg) * 4 + q;
                float v = acc[i][j][q] + bv_;
                if (mode == 3) {
                    Cout[(size_t)gr * 1024 + c] = v;
                } else {
                    int b = gr >> 10, n = gr & 1023;
                    int h = c >> 6, d = c & 63;
                    size_t bhn = ((size_t)(b * 16 + h)) * 1024 + n;
                    if (mode == 1) {
                        if (n < NSTAT) v = statk[n * 1024 + c];
                        ushort kh, klo;
                        limb2(v, kh, klo);
                        size_t off = bhn * 64 + (size_t)(((d >> 3) ^ (n & 7)) * 8) + (d & 7);
                        KHo[off] = kh;
                        KLo[off] = klo;
                    } else {
                        float* Out = (mode == 0) ? Qw : Vw;
                        Out[bhn * 64 + d] = v;
                    }
                }
            }
        }
    }
}

// ---------------- radix-select stage, 7-bit bins, padded hist[bin*33 + r] ----------------
__device__ __forceinline__ void radix_stage7(int* __restrict__ hist, int r, int l,
                                             const unsigned* __restrict__ ku,
                                             unsigned pref, unsigned mask, int shift,
                                             int tgt, int2* __restrict__ piv)
{
    #pragma unroll
    for (int b = 0; b < 8; ++b) hist[(l*8 + b)*33 + r] = 0;
    __syncthreads();
    #pragma unroll
    for (int j = 0; j < 64; ++j) {
        unsigned k = ku[j];
        if ((k & mask) == pref)
            atomicAdd(&hist[(int)((k >> shift) & 127u)*33 + r], 1);
    }
    __syncthreads();
    int seg = 0;
    #pragma unroll
    for (int b = 0; b < 8; ++b) seg += hist[(l*8 + b)*33 + r];
    int suf = seg;
    #pragma unroll
    for (int off = 1; off < 16; off <<= 1) {
        int v = __shfl_down(suf, off, 16);
        suf += (l + off < 16) ? v : 0;
    }
    const int above = suf - seg;
    if (above < tgt && above + seg >= tgt) {
        int c = above;
        #pragma unroll
        for (int b = 7; b >= 0; --b) {
            int h = hist[(l*8 + b)*33 + r];
            if (c + h >= tgt) { piv[r] = make_int2(l*8 + b, tgt - c); break; }
            c += h;
        }
    }
    __syncthreads();
}

// ---------------- MFMA attn (R15 structure, 48KB LDS -> 3 blocks/CU) ----------------
// ownership: lane (r=t>>4, l=t&15) owns keys {c*128 + l*8 + e}, slot j = c*8+e.
// LDS lifetime: [0,32768) Klds -> hist(16896)/sel(19456) + piv/cnt/rowsum at +20480
//               [32768,49152) Qs[32][68] -> sc[32][128] (XOR bank-swizzled)
// sc swizzle: col' = col ^ ((row&3)<<2) ^ (((row>>2)&1)<<4)  (stores & pulls both <=2-way)
__global__ __launch_bounds__(512, 4)
void attn_mfma_kernel(const float* __restrict__ Qw,
                      const ushort* __restrict__ KH, const ushort* __restrict__ KL,
                      const float* __restrict__ Vw, float* __restrict__ outp)
{
    __shared__ __align__(16) char pool[49152];   // exactly 48KB = 6 x 8KB granules

    ushort* Klds0 = (ushort*)pool;
    ushort* Klds1 = Klds0 + 8192;
    int* hist = (int*)pool;
    uint2 (*sel)[MAXSEL] = (uint2(*)[MAXSEL])pool;
    int2*  piv    = (int2*)(pool + 20480);        // dead-Klds region, after sel's 19456
    int*   cnt    = (int*)(pool + 20992);
    float* rowsum = (float*)(pool + 21248);
    float (*Qs)[68]  = (float(*)[68])(pool + 32768);
    float (*sc)[128] = (float(*)[128])(pool + 32768);

    const int t = threadIdx.x;
    const int bid0 = blockIdx.x;
    const int bid = (bid0 & 7) * 256 + (bid0 >> 3);   // XCD-bijective (2048 = 8*256)
    const int qt = bid & 31;
    const int bh = bid >> 5;
    const int n0 = qt * 32;
    const float* Qbase = Qw + ((size_t)bh * 1024 + n0) * 64;
    const float* Vbase = Vw + (size_t)bh * 1024 * 64;
    const ushort* KHb = KH + (size_t)bh * 1024 * 64;
    const ushort* KLb = KL + (size_t)bh * 1024 * 64;

    const int ll = t & 63;
    const int w  = t >> 6;               // 0..7
    const int qh = w >> 2;               // query half (16 rows)
    const int kr = w & 3;                // key range (32 keys of 128-key chunk)
    const int r  = t >> 4, l = t & 15;   // owner layout

    {
        int q = t >> 4, dq = (t & 15) * 4;
        *(float4*)&Qs[q][dq] = *(const float4*)(Qbase + q * 64 + dq);
    }
    auto stageK = [&](int c) {
        const size_t cb = (size_t)c * 8192;
        #pragma unroll
        for (int i = 0; i < 2; ++i) {
            int boff = i * 8192 + w * 1024;
            GLOAD_LDS16(KHb + cb + boff / 2 + ll * 8, ((char*)Klds0) + boff);
            GLOAD_LDS16(KLb + cb + boff / 2 + ll * 8, ((char*)Klds1) + boff);
        }
    };
    stageK(0);
    __syncthreads();

    // A fragments (Q 2-limb) for this wave's 16 query rows
    bf16x8_t aH[2], aL[2];
    {
        const int arow = qh * 16 + (ll & 15), akg = ll >> 4;
        #pragma unroll
        for (int s = 0; s < 2; ++s) {
            const float* qp = &Qs[arow][s*32 + akg*8];
            float4 q0 = *(const float4*)qp;
            float4 q1 = *(const float4*)(qp + 4);
            float qv[8] = {q0.x,q0.y,q0.z,q0.w,q1.x,q1.y,q1.z,q1.w};
            #pragma unroll
            for (int j = 0; j < 8; ++j) {
                ushort hh, lo2;
                limb2(qv[j], hh, lo2);
                aH[s][j] = (short)hh; aL[s][j] = (short)lo2;
            }
        }
    }
    __syncthreads();   // all Qs reads done before sc (alias) is first written

    unsigned ku[64];

    #pragma unroll
    for (int c = 0; c < 8; ++c) {
        // scores: wave (qh,kr) computes rows [qh*16,+16) x keys [kr*32,+32)
        #pragma unroll
        for (int tile = 0; tile < 2; ++tile) {
            const int m0 = kr * 32 + tile * 16;
            const int brow = m0 + (ll & 15);
            f32x4_t a_ = {0.f, 0.f, 0.f, 0.f};
            #pragma unroll
            for (int s = 0; s < 2; ++s) {
                int q2 = (s*4 + (ll >> 4)) ^ (brow & 7);
                int off = brow*64 + q2*8;
                bf16x8_t bH = *(const bf16x8_t*)&Klds0[off];
                bf16x8_t bL = *(const bf16x8_t*)&Klds1[off];
                a_ = __builtin_amdgcn_mfma_f32_16x16x32_bf16(aH[s], bH, a_, 0, 0, 0);
                a_ = __builtin_amdgcn_mfma_f32_16x16x32_bf16(aH[s], bL, a_, 0, 0, 0);
                a_ = __builtin_amdgcn_mfma_f32_16x16x32_bf16(aL[s], bH, a_, 0, 0, 0);
            }
            const int qr = qh * 16 + (ll >> 4) * 4;
            const int mcol = m0 + (ll & 15);
            const int swz = ((qr >> 2) & 1) << 4;     // (qr+i)>>2 == qr>>2 for i<4
            sc[qr+0][(mcol ^ 0)  ^ swz] = a_[0];
            sc[qr+1][(mcol ^ 4)  ^ swz] = a_[1];
            sc[qr+2][(mcol ^ 8)  ^ swz] = a_[2];
            sc[qr+3][(mcol ^ 12) ^ swz] = a_[3];
        }
        __syncthreads();

        if (c < 7) stageK(c + 1);
        {
            const int swz = ((r & 3) << 2) ^ (((r >> 2) & 1) << 4);
            float4 v0 = *(const float4*)&sc[r][(l*8) ^ swz];
            float4 v1 = *(const float4*)&sc[r][(l*8 + 4) ^ swz];
            float vv[8] = {v0.x,v0.y,v0.z,v0.w,v1.x,v1.y,v1.z,v1.w};
            #pragma unroll
            for (int e = 0; e < 8; ++e) {
                float vc = fminf(fmaxf(vv[e], -31.9f), 31.9f);
                ku[c*8 + e] = (unsigned)(int)fmaf(vc, 32768.f, 1048576.f);
            }
        }
        __syncthreads();   // staging landed + sc reads done
    }

    // Klds now dead: zero cnt (lives in dead-Klds region); ordered by radix's internal barriers
    if (t < 32) cnt[t] = 0;

    // ---- exact 64th-largest via 3-stage 7-bit radix (bits [20:14],[13:7],[6:0]) ----
    int tgt = 64;
    radix_stage7(hist, r, l, ku, 0u, 0u, 14, tgt, piv);
    unsigned pref = (unsigned)piv[r].x << 14; tgt = piv[r].y;
    radix_stage7(hist, r, l, ku, pref, 0x1FC000u, 7, tgt, piv);
    pref |= (unsigned)piv[r].x << 7; tgt = piv[r].y;
    radix_stage7(hist, r, l, ku, pref, 0x1FFF80u, 0, tgt, piv);
    const unsigned thr = pref | (unsigned)piv[r].x;

    // ---- lean selection: store (idx, k) for all k >= thr-2; classify in post-pass ----
    const unsigned bhi = thr + 2u;
    const unsigned blo = thr - 2u;                    // thr >= 3278, no underflow
    #pragma unroll
    for (int j = 0; j < 64; ++j) {
        unsigned k = ku[j];
        if (k >= blo) {
            int slot = atomicAdd(&cnt[r], 1);
            if (slot < MAXSEL)
                sel[r][slot] = make_uint2((unsigned)((j >> 3)*128 + l*8 + (j & 7)), k);
        }
    }
    __syncthreads();

    // ---- post-pass: thr-referenced weights, frac for boundary, rowsum (16 lanes/row) ----
    {
        int cc = cnt[r]; cc = (cc < MAXSEL) ? cc : MAXSEL;
        int Dl = 0, ml = 0;
        for (int j = l; j < cc; j += 16) {
            unsigned k = sel[r][j].y;
            if (k > bhi) Dl++; else ml++;
        }
        #pragma unroll
        for (int off = 8; off; off >>= 1) {
            Dl += __shfl_xor(Dl, off, 16);
            ml += __shfl_xor(ml, off, 16);
        }
        const float frac = (float)(64 - Dl) / (float)ml;
        float ls = 0.f;
        for (int j = l; j < cc; j += 16) {
            uint2 p = sel[r][j];
            float wgt = __expf((float)(int)(p.y - thr) * 3.814697265625e-6f);
            if (p.y <= bhi) wgt *= frac;
            p.y = __float_as_uint(wgt);
            sel[r][j] = p;
            ls += wgt;
        }
        #pragma unroll
        for (int off = 8; off; off >>= 1) ls += __shfl_xor(ls, off, 16);
        if (l == 0) { rowsum[r] = ls; cnt[r] = cc; }
    }
    __syncthreads();

    // ---- PV: thread = (row, d-quad); float4 V gathers ----
    {
        const int pr = t >> 4;
        const int d4 = (t & 15) * 4;
        const int bb = bh >> 4, hh = bh & 15;
        const int cc = cnt[pr];
        float4 a = make_float4(0.f, 0.f, 0.f, 0.f);
        int j = 0;
        for (; j + 1 < cc; j += 2) {
            uint2 p0 = sel[pr][j];
            uint2 p1 = sel[pr][j+1];
            float w0 = __uint_as_float(p0.y);
            float w1 = __uint_as_float(p1.y);
            float4 v0 = *(const float4*)(Vbase + (size_t)p0.x * 64 + d4);
            float4 v1 = *(const float4*)(Vbase + (size_t)p1.x * 64 + d4);
            a.x += w0 * v0.x + w1 * v1.x;
            a.y += w0 * v0.y + w1 * v1.y;
            a.z += w0 * v0.z + w1 * v1.z;
            a.w += w0 * v0.w + w1 * v1.w;
        }
        if (j < cc) {
            uint2 p = sel[pr][j];
            float wv = __uint_as_float(p.y);
            float4 v = *(const float4*)(Vbase + (size_t)p.x * 64 + d4);
            a.x += wv * v.x; a.y += wv * v.y; a.z += wv * v.z; a.w += wv * v.w;
        }
        float inv = 1.0f / rowsum[pr];
        a.x *= inv; a.y *= inv; a.z *= inv; a.w *= inv;
        *(float4*)(outp + ((size_t)bb * 1024 + (n0 + pr)) * 1024 + hh * 64 + d4) = a;
    }
}

extern "C" void kernel_launch(void* const* d_in, const int* in_sizes, int n_in,
                              void* d_out, int out_size, void* d_ws, size_t ws_size,
                              hipStream_t stream) {
    const float* x     = (const float*)d_in[0];
    const float* Wq    = (const float*)d_in[1];
    const float* bq    = (const float*)d_in[2];
    const float* Wk    = (const float*)d_in[3];
    const float* bk    = (const float*)d_in[4];
    const float* Wv    = (const float*)d_in[5];
    const float* bv    = (const float*)d_in[6];
    const float* Wo    = (const float*)d_in[7];
    const float* bo    = (const float*)d_in[8];
    const float* statk = (const float*)d_in[9];
    float* out = (float*)d_out;
    char* base = (char*)d_ws;

    const size_t MiB = (size_t)1 << 20;
    // ws: [0,16) Qw | [16,32) Vw | [32,40) KH | [40,48) KL | [48,52) WoLb | [52,64) WLq
    // op f32 [52,68) aliases WLq after the QKV GEMMs are done.
    float*  Qw   = (float*)(base);
    float*  Vw   = (float*)(base + 16*MiB);
    ushort* KH   = (ushort*)(base + 32*MiB);
    ushort* KL   = (ushort*)(base + 40*MiB);
    ushort* WoLb = (ushort*)(base + 48*MiB);
    ushort* WLq  = (ushort*)(base + 52*MiB);
    float*  op   = (float*)(base + 52*MiB);

    dim3 gd(512, 4);
    decomp_w_kernel<<<gd, 256, 0, stream>>>(Wq, Wk, Wv, Wo, WLq, WoLb);

    dim3 g1(8, 32, 3);
    limb_gemm_kernel<<<g1, 256, 0, stream>>>(x, WLq, WoLb, bq, bk, bv, bo, statk,
                                             Qw, Vw, KH, KL, nullptr, 0);

    attn_mfma_kernel<<<2048, 512, 0, stream>>>(Qw, KH, KL, Vw, op);

    dim3 g2(8, 32);
    limb_gemm_kernel<<<g2, 256, 0, stream>>>(op, WLq, WoLb, bq, bk, bv, bo, statk,
                                             Qw, Vw, KH, KL, out, 1);
}

// Round 20
// 292.063 us; speedup vs baseline: 1.0163x; 1.0163x over previous
//
#include <hip/hip_runtime.h>

#define NSTAT 32
#define MAXSEL 76

typedef __attribute__((ext_vector_type(8))) short bf16x8_t;
typedef __attribute__((ext_vector_type(4))) float f32x4_t;

#define GLOAD_LDS16(g, l) \
    __builtin_amdgcn_global_load_lds((const __attribute__((address_space(1))) void*)(g), \
                                     (__attribute__((address_space(3))) void*)(l), 16, 0, 0)

// round-to-nearest-even bf16
__device__ __forceinline__ ushort rtn_bf16(float a) {
    unsigned u = __float_as_uint(a);
    return (ushort)((u + 0x7FFFu + ((u >> 16) & 1u)) >> 16);
}
// 2-limb RTN decomposition: a ~= hi + lo, |residual| <= 2^-18 |a|
__device__ __forceinline__ void limb2(float a, ushort& h, ushort& l) {
    ushort hh = rtn_bf16(a);
    float fh = __uint_as_float(((unsigned)hh) << 16);
    float r1 = a - fh;
    l = rtn_bf16(r1);
    h = hh;
}

// ---------------- weight 2-limb decomposition (pre-swizzled tile layout) ----------------
__global__ __launch_bounds__(256)
void decomp_w_kernel(const float* __restrict__ Wq, const float* __restrict__ Wk,
                     const float* __restrict__ Wv, const float* __restrict__ Wo,
                     ushort* __restrict__ WLq, ushort* __restrict__ WoLb)
{
    const int m = blockIdx.y;
    const float* src = (m == 0) ? Wq : (m == 1) ? Wk : (m == 2) ? Wv : Wo;
    const int idx = blockIdx.x * 256 + threadIdx.x;
    const int e8 = idx * 8;
    const int row = e8 >> 10, k0 = e8 & 1023;
    const int kt = k0 >> 5, q = (k0 >> 3) & 3;
    const size_t doff = ((size_t)row << 10) + (size_t)(kt * 32) + (size_t)((q ^ (row & 3)) * 8);

    float4 v0 = *(const float4*)(src + e8);
    float4 v1 = *(const float4*)(src + e8 + 4);
    float f[8] = {v0.x, v0.y, v0.z, v0.w, v1.x, v1.y, v1.z, v1.w};

    const size_t Mi = (size_t)1 << 20;
    ushort h[8], l[8];
    #pragma unroll
    for (int e = 0; e < 8; ++e) limb2(f[e], h[e], l[e]);
    ushort* H = (m == 3) ? WoLb : WLq + (size_t)(m * 2) * Mi;
    ushort* L = H + Mi;
    *(ushort4*)(H + doff)     = make_ushort4(h[0],h[1],h[2],h[3]);
    *(ushort4*)(H + doff + 4) = make_ushort4(h[4],h[5],h[6],h[7]);
    *(ushort4*)(L + doff)     = make_ushort4(l[0],l[1],l[2],l[3]);
    *(ushort4*)(L + doff + 4) = make_ushort4(l[4],l[5],l[6],l[7]);
}

// ---------------- 2-limb MFMA GEMM (R8-validated; A fp32 on-the-fly) ----------------
__global__ __launch_bounds__(256, 3)
void limb_gemm_kernel(const float* __restrict__ A,
                      const ushort* __restrict__ WLq, const ushort* __restrict__ WoLb,
                      const float* __restrict__ bq, const float* __restrict__ bk,
                      const float* __restrict__ bv, const float* __restrict__ bo,
                      const float* __restrict__ statk,
                      float* __restrict__ Qw, float* __restrict__ Vw,
                      ushort* __restrict__ KHo, ushort* __restrict__ KLo,
                      float* __restrict__ Cout, int is_out)
{
    __shared__ __align__(16) ushort Al[2][128][32];
    __shared__ __align__(16) ushort Bl[2][2][128][32];

    const int t = threadIdx.x;
    const int bx = blockIdx.x, by = blockIdx.y;
    const int mode = is_out ? 3 : (int)blockIdx.z;
    const int wc0 = bx * 128;
    const int arow0 = by * 128;

    const size_t Mi = (size_t)1 << 20;
    const ushort* BpH;
    const float* bias;
    if (mode == 0)      { BpH = WLq;          bias = bq; }
    else if (mode == 1) { BpH = WLq + 2*Mi;   bias = bk; }
    else if (mode == 2) { BpH = WLq + 4*Mi;   bias = bv; }
    else                { BpH = WoLb;         bias = bo; }
    const ushort* BpL = BpH + Mi;

    const int ll = t & 63, w = t >> 6;

    f32x4_t acc[4][4];
    #pragma unroll
    for (int i = 0; i < 4; ++i)
        #pragma unroll
        for (int j = 0; j < 4; ++j) acc[i][j] = (f32x4_t){0.f, 0.f, 0.f, 0.f};

    auto stageB = [&](int kt, int bb) {
        #pragma unroll
        for (int limb = 0; limb < 2; ++limb) {
            const ushort* src = limb ? BpL : BpH;
            #pragma unroll
            for (int call = 0; call < 2; ++call) {
                int chunk = (w * 2 + call) * 64 + ll;
                int eoff = chunk * 8;
                int row = eoff >> 5, qp = (eoff >> 3) & 3;
                const ushort* g = src + ((size_t)(wc0 + row) << 10) + kt * 32 + qp * 8;
                char* l = ((char*)&Bl[bb][limb][0][0]) + (w * 2 + call) * 1024;
                GLOAD_LDS16(g, l);
            }
        }
    };
    const int srow = t >> 1, skh = (t & 1) * 16;
    auto loadA = [&](int kt, float4* a4) {
        const float* p = A + (((size_t)(arow0 + srow)) << 10) + kt * 32 + skh;
        a4[0] = *(const float4*)(p + 0);
        a4[1] = *(const float4*)(p + 4);
        a4[2] = *(const float4*)(p + 8);
        a4[3] = *(const float4*)(p + 12);
    };
    auto writeA = [&](const float4* a4) {
        float f[16];
        #pragma unroll
        for (int i = 0; i < 4; ++i) {
            f[i*4+0] = a4[i].x; f[i*4+1] = a4[i].y; f[i*4+2] = a4[i].z; f[i*4+3] = a4[i].w;
        }
        ushort h[16], lo[16];
        #pragma unroll
        for (int e = 0; e < 16; ++e) limb2(f[e], h[e], lo[e]);
        const int sw = srow & 3;
        #pragma unroll
        for (int qq = 0; qq < 2; ++qq) {
            int q = (skh >> 3) + qq;
            int qo = (q ^ sw) * 8;
            bf16x8_t vH, vL;
            #pragma unroll
            for (int e = 0; e < 8; ++e) {
                vH[e] = (short)h[qq*8+e]; vL[e] = (short)lo[qq*8+e];
            }
            *(bf16x8_t*)&Al[0][srow][qo] = vH;
            *(bf16x8_t*)&Al[1][srow][qo] = vL;
        }
    };

    const int wr = (w >> 1) * 64, wcv = (w & 1) * 64;
    const int fr = ll & 15, kg = ll >> 4;

    auto compute = [&](int bb) {
        bf16x8_t af[4][2];
        #pragma unroll
        for (int i = 0; i < 4; ++i) {
            int row = wr + i * 16 + fr;
            int qo = (kg ^ (row & 3)) * 8;
            af[i][0] = *(const bf16x8_t*)&Al[0][row][qo];
            af[i][1] = *(const bf16x8_t*)&Al[1][row][qo];
        }
        #pragma unroll
        for (int j = 0; j < 4; ++j) {
            int row = wcv + j * 16 + fr;
            int qo = (kg ^ (row & 3)) * 8;
            bf16x8_t b0 = *(const bf16x8_t*)&Bl[bb][0][row][qo];
            bf16x8_t b1 = *(const bf16x8_t*)&Bl[bb][1][row][qo];
            #pragma unroll
            for (int i = 0; i < 4; ++i) {
                acc[i][j] = __builtin_amdgcn_mfma_f32_16x16x32_bf16(af[i][0], b0, acc[i][j], 0, 0, 0);
                acc[i][j] = __builtin_amdgcn_mfma_f32_16x16x32_bf16(af[i][0], b1, acc[i][j], 0, 0, 0);
                acc[i][j] = __builtin_amdgcn_mfma_f32_16x16x32_bf16(af[i][1], b0, acc[i][j], 0, 0, 0);
            }
        }
    };

    float4 a4[4];
    loadA(0, a4);
    writeA(a4);
    stageB(0, 0);
    __syncthreads();

    float4 a4n[4];
    for (int kt = 0; kt < 32; ++kt) {
        int bb = kt & 1;
        if (kt < 31) {
            stageB(kt + 1, bb ^ 1);
            loadA(kt + 1, a4n);
        }
        compute(bb);
        __syncthreads();
        if (kt < 31) writeA(a4n);
        __syncthreads();
    }

    #pragma unroll
    for (int i = 0; i < 4; ++i) {
        #pragma unroll
        for (int j = 0; j < 4; ++j) {
            int c = wc0 + wcv + j * 16 + (ll & 15);
            float bv_ = bias[c];
            #pragma unroll
            for (int q = 0; q < 4; ++q) {
                int gr = arow0 + wr + i * 16 + (kg) * 4 + q;
                float v = acc[i][j][q] + bv_;
                if (mode == 3) {
                    Cout[(size_t)gr * 1024 + c] = v;
                } else {
                    int b = gr >> 10, n = gr & 1023;
                    int h = c >> 6, d = c & 63;
                    size_t bhn = ((size_t)(b * 16 + h)) * 1024 + n;
                    if (mode == 1) {
                        if (n < NSTAT) v = statk[n * 1024 + c];
                        ushort kh, klo;
                        limb2(v, kh, klo);
                        size_t off = bhn * 64 + (size_t)(((d >> 3) ^ (n & 7)) * 8) + (d & 7);
                        KHo[off] = kh;
                        KLo[off] = klo;
                    } else {
                        float* Out = (mode == 0) ? Qw : Vw;
                        Out[bhn * 64 + d] = v;
                    }
                }
            }
        }
    }
}

// ---------------- radix-select stage, 7-bit bins, padded hist[bin*33 + r] ----------------
__device__ __forceinline__ void radix_stage7(int* __restrict__ hist, int r, int l,
                                             const unsigned* __restrict__ ku,
                                             unsigned pref, unsigned mask, int shift,
                                             int tgt, int2* __restrict__ piv)
{
    #pragma unroll
    for (int b = 0; b < 8; ++b) hist[(l*8 + b)*33 + r] = 0;
    __syncthreads();
    #pragma unroll
    for (int j = 0; j < 64; ++j) {
        unsigned k = ku[j];
        if ((k & mask) == pref)
            atomicAdd(&hist[(int)((k >> shift) & 127u)*33 + r], 1);
    }
    __syncthreads();
    int seg = 0;
    #pragma unroll
    for (int b = 0; b < 8; ++b) seg += hist[(l*8 + b)*33 + r];
    int suf = seg;
    #pragma unroll
    for (int off = 1; off < 16; off <<= 1) {
        int v = __shfl_down(suf, off, 16);
        suf += (l + off < 16) ? v : 0;
    }
    const int above = suf - seg;
    if (above < tgt && above + seg >= tgt) {
        int c = above;
        #pragma unroll
        for (int b = 7; b >= 0; --b) {
            int h = hist[(l*8 + b)*33 + r];
            if (c + h >= tgt) { piv[r] = make_int2(l*8 + b, tgt - c); break; }
            c += h;
        }
    }
    __syncthreads();
}

// ---------------- MFMA attn (R19 structure + double-buffered K, PV unroll-4) ----------------
// ownership: lane (r=t>>4, l=t&15) owns keys {c*128 + l*8 + e}, slot j = c*8+e.
// LDS: [0,65536) Klds dbuf {buf kb at kb*32768: H 16K, L 16K}
//      -> after chunk loop: hist(16896)/sel(19456) + piv/cnt/rowsum at +20480 (dead buf0)
//      [65536,81920) sc[32][128] XOR-swizzled; Qs[32][68] aliases its start
__global__ __launch_bounds__(512, 4)
void attn_mfma_kernel(const float* __restrict__ Qw,
                      const ushort* __restrict__ KH, const ushort* __restrict__ KL,
                      const float* __restrict__ Vw, float* __restrict__ outp)
{
    __shared__ __align__(16) char pool[81920];

    int* hist = (int*)pool;
    uint2 (*sel)[MAXSEL] = (uint2(*)[MAXSEL])pool;
    int2*  piv    = (int2*)(pool + 20480);
    int*   cnt    = (int*)(pool + 20992);
    float* rowsum = (float*)(pool + 21248);
    float (*Qs)[68]  = (float(*)[68])(pool + 65536);
    float (*sc)[128] = (float(*)[128])(pool + 65536);

    const int t = threadIdx.x;
    const int bid0 = blockIdx.x;
    const int bid = (bid0 & 7) * 256 + (bid0 >> 3);   // XCD-bijective (2048 = 8*256)
    const int qt = bid & 31;
    const int bh = bid >> 5;
    const int n0 = qt * 32;
    const float* Qbase = Qw + ((size_t)bh * 1024 + n0) * 64;
    const float* Vbase = Vw + (size_t)bh * 1024 * 64;
    const ushort* KHb = KH + (size_t)bh * 1024 * 64;
    const ushort* KLb = KL + (size_t)bh * 1024 * 64;

    const int ll = t & 63;
    const int w  = t >> 6;               // 0..7
    const int qh = w >> 2;               // query half (16 rows)
    const int kr = w & 3;                // key range (32 keys of 128-key chunk)
    const int r  = t >> 4, l = t & 15;   // owner layout

    {
        int q = t >> 4, dq = (t & 15) * 4;
        *(float4*)&Qs[q][dq] = *(const float4*)(Qbase + q * 64 + dq);
    }
    auto stageK = [&](int c, int kb) {
        const size_t cb = (size_t)c * 8192;
        char* dbase = pool + kb * 32768;
        #pragma unroll
        for (int i = 0; i < 2; ++i) {
            int boff = i * 8192 + w * 1024;
            GLOAD_LDS16(KHb + cb + boff / 2 + ll * 8, dbase + boff);
            GLOAD_LDS16(KLb + cb + boff / 2 + ll * 8, dbase + 16384 + boff);
        }
    };
    stageK(0, 0);
    __syncthreads();

    // A fragments (Q 2-limb) for this wave's 16 query rows
    bf16x8_t aH[2], aL[2];
    {
        const int arow = qh * 16 + (ll & 15), akg = ll >> 4;
        #pragma unroll
        for (int s = 0; s < 2; ++s) {
            const float* qp = &Qs[arow][s*32 + akg*8];
            float4 q0 = *(const float4*)qp;
            float4 q1 = *(const float4*)(qp + 4);
            float qv[8] = {q0.x,q0.y,q0.z,q0.w,q1.x,q1.y,q1.z,q1.w};
            #pragma unroll
            for (int j = 0; j < 8; ++j) {
                ushort hh, lo2;
                limb2(qv[j], hh, lo2);
                aH[s][j] = (short)hh; aL[s][j] = (short)lo2;
            }
        }
    }
    __syncthreads();   // all Qs reads done before sc (alias) is first written

    unsigned ku[64];

    #pragma unroll
    for (int c = 0; c < 8; ++c) {
        const int kb = c & 1;
        if (c < 7) stageK(c + 1, kb ^ 1);      // issue early into idle buffer
        const ushort* Klds0 = (const ushort*)(pool + kb * 32768);
        const ushort* Klds1 = Klds0 + 8192;

        // scores: wave (qh,kr) computes rows [qh*16,+16) x keys [kr*32,+32)
        #pragma unroll
        for (int tile = 0; tile < 2; ++tile) {
            const int m0 = kr * 32 + tile * 16;
            const int brow = m0 + (ll & 15);
            f32x4_t a_ = {0.f, 0.f, 0.f, 0.f};
            #pragma unroll
            for (int s = 0; s < 2; ++s) {
                int q2 = (s*4 + (ll >> 4)) ^ (brow & 7);
                int off = brow*64 + q2*8;
                bf16x8_t bH = *(const bf16x8_t*)&Klds0[off];
                bf16x8_t bL = *(const bf16x8_t*)&Klds1[off];
                a_ = __builtin_amdgcn_mfma_f32_16x16x32_bf16(aH[s], bH, a_, 0, 0, 0);
                a_ = __builtin_amdgcn_mfma_f32_16x16x32_bf16(aH[s], bL, a_, 0, 0, 0);
                a_ = __builtin_amdgcn_mfma_f32_16x16x32_bf16(aL[s], bH, a_, 0, 0, 0);
            }
            const int qr = qh * 16 + (ll >> 4) * 4;
            const int mcol = m0 + (ll & 15);
            const int swz = ((qr >> 2) & 1) << 4;     // (qr+i)>>2 == qr>>2 for i<4
            sc[qr+0][(mcol ^ 0)  ^ swz] = a_[0];
            sc[qr+1][(mcol ^ 4)  ^ swz] = a_[1];
            sc[qr+2][(mcol ^ 8)  ^ swz] = a_[2];
            sc[qr+3][(mcol ^ 12) ^ swz] = a_[3];
        }
        __syncthreads();   // sc ready; staging (issued at top) drains here, hidden under compute

        {
            const int swz = ((r & 3) << 2) ^ (((r >> 2) & 1) << 4);
            float4 v0 = *(const float4*)&sc[r][(l*8) ^ swz];
            float4 v1 = *(const float4*)&sc[r][(l*8 + 4) ^ swz];
            float vv[8] = {v0.x,v0.y,v0.z,v0.w,v1.x,v1.y,v1.z,v1.w};
            #pragma unroll
            for (int e = 0; e < 8; ++e) {
                float vc = fminf(fmaxf(vv[e], -31.9f), 31.9f);
                ku[c*8 + e] = (unsigned)(int)fmaf(vc, 32768.f, 1048576.f);
            }
        }
        __syncthreads();   // sc pulls done before next chunk's sc writes
    }

    // Klds dead: zero cnt (in dead buf0); ordered by radix's internal barriers
    if (t < 32) cnt[t] = 0;

    // ---- exact 64th-largest via 3-stage 7-bit radix (bits [20:14],[13:7],[6:0]) ----
    int tgt = 64;
    radix_stage7(hist, r, l, ku, 0u, 0u, 14, tgt, piv);
    unsigned pref = (unsigned)piv[r].x << 14; tgt = piv[r].y;
    radix_stage7(hist, r, l, ku, pref, 0x1FC000u, 7, tgt, piv);
    pref |= (unsigned)piv[r].x << 7; tgt = piv[r].y;
    radix_stage7(hist, r, l, ku, pref, 0x1FFF80u, 0, tgt, piv);
    const unsigned thr = pref | (unsigned)piv[r].x;

    // ---- lean selection: store (idx, k) for all k >= thr-2; classify in post-pass ----
    const unsigned bhi = thr + 2u;
    const unsigned blo = thr - 2u;                    // thr >= 3278, no underflow
    #pragma unroll
    for (int j = 0; j < 64; ++j) {
        unsigned k = ku[j];
        if (k >= blo) {
            int slot = atomicAdd(&cnt[r], 1);
            if (slot < MAXSEL)
                sel[r][slot] = make_uint2((unsigned)((j >> 3)*128 + l*8 + (j & 7)), k);
        }
    }
    __syncthreads();

    // ---- post-pass: thr-referenced weights, frac for boundary, rowsum (16 lanes/row) ----
    {
        int cc = cnt[r]; cc = (cc < MAXSEL) ? cc : MAXSEL;
        int Dl = 0, ml = 0;
        for (int j = l; j < cc; j += 16) {
            unsigned k = sel[r][j].y;
            if (k > bhi) Dl++; else ml++;
        }
        #pragma unroll
        for (int off = 8; off; off >>= 1) {
            Dl += __shfl_xor(Dl, off, 16);
            ml += __shfl_xor(ml, off, 16);
        }
        const float frac = (float)(64 - Dl) / (float)ml;
        float ls = 0.f;
        for (int j = l; j < cc; j += 16) {
            uint2 p = sel[r][j];
            float wgt = __expf((float)(int)(p.y - thr) * 3.814697265625e-6f);
            if (p.y <= bhi) wgt *= frac;
            p.y = __float_as_uint(wgt);
            sel[r][j] = p;
            ls += wgt;
        }
        #pragma unroll
        for (int off = 8; off; off >>= 1) ls += __shfl_xor(ls, off, 16);
        if (l == 0) { rowsum[r] = ls; cnt[r] = cc; }
    }
    __syncthreads();

    // ---- PV: thread = (row, d-quad); float4 V gathers, 4-deep ILP ----
    {
        const int pr = t >> 4;
        const int d4 = (t & 15) * 4;
        const int bb = bh >> 4, hh = bh & 15;
        const int cc = cnt[pr];
        float4 a = make_float4(0.f, 0.f, 0.f, 0.f);
        int j = 0;
        for (; j + 3 < cc; j += 4) {
            uint2 p0 = sel[pr][j];
            uint2 p1 = sel[pr][j+1];
            uint2 p2 = sel[pr][j+2];
            uint2 p3 = sel[pr][j+3];
            float w0 = __uint_as_float(p0.y);
            float w1 = __uint_as_float(p1.y);
            float w2 = __uint_as_float(p2.y);
            float w3 = __uint_as_float(p3.y);
            float4 v0 = *(const float4*)(Vbase + (size_t)p0.x * 64 + d4);
            float4 v1 = *(const float4*)(Vbase + (size_t)p1.x * 64 + d4);
            float4 v2 = *(const float4*)(Vbase + (size_t)p2.x * 64 + d4);
            float4 v3 = *(const float4*)(Vbase + (size_t)p3.x * 64 + d4);
            a.x += w0 * v0.x + w1 * v1.x + w2 * v2.x + w3 * v3.x;
            a.y += w0 * v0.y + w1 * v1.y + w2 * v2.y + w3 * v3.y;
            a.z += w0 * v0.z + w1 * v1.z + w2 * v2.z + w3 * v3.z;
            a.w += w0 * v0.w + w1 * v1.w + w2 * v2.w + w3 * v3.w;
        }
        for (; j < cc; ++j) {
            uint2 p = sel[pr][j];
            float wv = __uint_as_float(p.y);
            float4 v = *(const float4*)(Vbase + (size_t)p.x * 64 + d4);
            a.x += wv * v.x; a.y += wv * v.y; a.z += wv * v.z; a.w += wv * v.w;
        }
        float inv = 1.0f / rowsum[pr];
        a.x *= inv; a.y *= inv; a.z *= inv; a.w *= inv;
        *(float4*)(outp + ((size_t)bb * 1024 + (n0 + pr)) * 1024 + hh * 64 + d4) = a;
    }
}

extern "C" void kernel_launch(void* const* d_in, const int* in_sizes, int n_in,
                              void* d_out, int out_size, void* d_ws, size_t ws_size,
                              hipStream_t stream) {
    const float* x     = (const float*)d_in[0];
    const float* Wq    = (const float*)d_in[1];
    const float* bq    = (const float*)d_in[2];
    const float* Wk    = (const float*)d_in[3];
    const float* bk    = (const float*)d_in[4];
    const float* Wv    = (const float*)d_in[5];
    const float* bv    = (const float*)d_in[6];
    const float* Wo    = (const float*)d_in[7];
    const float* bo    = (const float*)d_in[8];
    const float* statk = (const float*)d_in[9];
    float* out = (float*)d_out;
    char* base = (char*)d_ws;

    const size_t MiB = (size_t)1 << 20;
    // ws: [0,16) Qw | [16,32) Vw | [32,40) KH | [40,48) KL | [48,52) WoLb | [52,64) WLq
    // op f32 [52,68) aliases WLq after the QKV GEMMs are done.
    float*  Qw   = (float*)(base);
    float*  Vw   = (float*)(base + 16*MiB);
    ushort* KH   = (ushort*)(base + 32*MiB);
    ushort* KL   = (ushort*)(base + 40*MiB);
    ushort* WoLb = (ushort*)(base + 48*MiB);
    ushort* WLq  = (ushort*)(base + 52*MiB);
    float*  op   = (float*)(base + 52*MiB);

    dim3 gd(512, 4);
    decomp_w_kernel<<<gd, 256, 0, stream>>>(Wq, Wk, Wv, Wo, WLq, WoLb);

    dim3 g1(8, 32, 3);
    limb_gemm_kernel<<<g1, 256, 0, stream>>>(x, WLq, WoLb, bq, bk, bv, bo, statk,
                                             Qw, Vw, KH, KL, nullptr, 0);

    attn_mfma_kernel<<<2048, 512, 0, stream>>>(Qw, KH, KL, Vw, op);

    dim3 g2(8, 32);
    limb_gemm_kernel<<<g2, 256, 0, stream>>>(op, WLq, WoLb, bq, bk, bv, bo, statk,
                                             Qw, Vw, KH, KL, out, 1);
}